// Round 5
// baseline (1484.219 us; speedup 1.0000x reference)
//
#include <hip/hip_runtime.h>

#define HID 16
#define NFEAT 512

__device__ __forceinline__ unsigned short f2b(float f) {
    unsigned u = __float_as_uint(f);
    unsigned r = (u + 0x7fffu + ((u >> 16) & 1u)) >> 16;   // RNE
    return (unsigned short)r;
}
__device__ __forceinline__ float b2f(unsigned short b) {
    return __uint_as_float(((unsigned)b) << 16);
}

// ---------------------------------------------------------------- degree
__global__ __launch_bounds__(256) void deg_count_int(const int* __restrict__ dst,
                                                     int* __restrict__ ideg, int e) {
    int i = blockIdx.x * 256 + threadIdx.x;
    if (i < e) atomicAdd(&ideg[dst[i]], 1);
}

__global__ __launch_bounds__(256) void make_dis(const int* __restrict__ ideg,
                                                float* __restrict__ dis, int n) {
    int i = blockIdx.x * 256 + threadIdx.x;
    if (i < n) dis[i] = rsqrtf(1.0f + (float)ideg[i]);
}

// ---------------------------------------------------------------- h1 = x @ W1
// Block = 256 thr = 16 rows x 16 k-chunks; acc[16] per thread (no spill).
// W1 staged TRANSPOSED in LDS (4-lane broadcast within wave; 2-way bank
// aliasing = free). x loads: 4 x 256B contiguous segments per wave instr.
// Epilogue also writes hs = h1*dis as bf16 for the propagation gather.
__global__ __launch_bounds__(256) void mm1(const float* __restrict__ x,
                                           const float* __restrict__ W1,
                                           const float* __restrict__ dis,
                                           float* __restrict__ h1,
                                           unsigned short* __restrict__ hsb, int n) {
    __shared__ float lds[NFEAT * HID];        // 32 KB: W1t, then reused as red[]
    float* W1t = lds;                         // [16][512]
    for (int idx = threadIdx.x; idx < NFEAT * HID / 4; idx += 256) {
        int k = idx >> 2, j0 = (idx & 3) * 4;
        float4 v = ((const float4*)W1)[idx];
        W1t[(j0 + 0) * NFEAT + k] = v.x;
        W1t[(j0 + 1) * NFEAT + k] = v.y;
        W1t[(j0 + 2) * NFEAT + k] = v.z;
        W1t[(j0 + 3) * NFEAT + k] = v.w;
    }
    __syncthreads();

    int r = threadIdx.x >> 4;                 // row within block
    int c = threadIdx.x & 15;                 // k-chunk
    int row = blockIdx.x * 16 + r;
    bool active = (row < n);

    float acc[HID];
#pragma unroll
    for (int j = 0; j < HID; ++j) acc[j] = 0.f;

    if (active) {
        const float4* xr = (const float4*)x + (size_t)row * (NFEAT / 4);
#pragma unroll
        for (int i = 0; i < 8; ++i) {
            float4 xv = xr[i * 16 + c];
            int kb = i * 64 + c * 4;
#pragma unroll
            for (int j = 0; j < HID; ++j) {
                float4 w = *(const float4*)&W1t[j * NFEAT + kb];
                acc[j] += xv.x * w.x + xv.y * w.y + xv.z * w.z + xv.w * w.w;
            }
        }
    }
    __syncthreads();   // done with W1t; reuse lds as red[16][16][17]

    float* red = lds;
#pragma unroll
    for (int j = 0; j < HID; ++j)
        red[r * 272 + c * 17 + j] = acc[j];
    __syncthreads();

    float sum = 0.f;
#pragma unroll
    for (int cc = 0; cc < 16; ++cc)
        sum += red[r * 272 + cc * 17 + c];
    if (active) {
        h1[(size_t)row * HID + c] = sum;
        hsb[(size_t)row * HID + c] = f2b(sum * dis[row]);
    }
}

// ---------------------------------------------------------------- propagation
// agg[d] += hs[s]  (hs already scaled by dis[s]; dis[d] applied per-node later)
// 4 lanes per edge, each loads 8B of bf16 and issues 4 fp32 atomics.
__global__ __launch_bounds__(256) void prop(const int* __restrict__ src,
                                            const int* __restrict__ dst,
                                            const unsigned short* __restrict__ hsb,
                                            float* __restrict__ agg, int e) {
    int idx = blockIdx.x * 256 + threadIdx.x;   // e*4 = 12.8M
    int ed = idx >> 2, l = idx & 3;
    if (ed >= e) return;
    int s = src[ed], d = dst[ed];
    ushort4 hv = *(const ushort4*)(hsb + (size_t)s * HID + l * 4);
    float* ar = agg + (size_t)d * HID + l * 4;
    atomicAdd(ar + 0, b2f(hv.x));
    atomicAdd(ar + 1, b2f(hv.y));
    atomicAdd(ar + 2, b2f(hv.z));
    atomicAdd(ar + 3, b2f(hv.w));
}

// ---------------------------------------------------------------- fused middle
// h = relu(dis*agg1 + dis^2*h1 + b1);  h2 = h @ W2; h2 -> h1, hs2 -> hsb
__global__ __launch_bounds__(256) void mid(const float* __restrict__ agg1,
                                           float* __restrict__ h1,
                                           unsigned short* __restrict__ hsb,
                                           const float* __restrict__ dis,
                                           const float* __restrict__ b1,
                                           const float* __restrict__ W2, int n) {
    __shared__ float W2s[HID * HID];
    W2s[threadIdx.x] = W2[threadIdx.x];
    __syncthreads();

    int idx = blockIdx.x * 256 + threadIdx.x;
    int v = idx >> 4, j = idx & 15;
    if (v >= n) return;
    float dn = dis[v];
    float a = dn * agg1[idx] + dn * dn * h1[idx] + b1[j];
    float hv = fmaxf(a, 0.f);
    float h2 = 0.f;
#pragma unroll
    for (int k = 0; k < HID; ++k)
        h2 += __shfl(hv, k, HID) * W2s[k * HID + j];
    h1[idx] = h2;
    hsb[idx] = f2b(h2 * dn);
}

// z = dis*agg2 + dis^2*h2 + b2;  out = z + eps*exp(0.5*z)  (agg2 lives in d_out)
__global__ __launch_bounds__(256) void finalk(float* __restrict__ out,
                                              const float* __restrict__ h2,
                                              const float* __restrict__ dis,
                                              const float* __restrict__ b2,
                                              const float* __restrict__ eps, int n) {
    int idx = blockIdx.x * 256 + threadIdx.x;
    int v = idx >> 4, j = idx & 15;
    if (v >= n) return;
    float dn = dis[v];
    float z = dn * out[idx] + dn * dn * h2[idx] + b2[j];
    out[idx] = z + eps[idx] * expf(0.5f * z);
}

extern "C" void kernel_launch(void* const* d_in, const int* in_sizes, int n_in,
                              void* d_out, int out_size, void* d_ws, size_t ws_size,
                              hipStream_t stream) {
    const float* x   = (const float*)d_in[0];
    const float* W1  = (const float*)d_in[1];
    const float* b1  = (const float*)d_in[2];
    const float* W2  = (const float*)d_in[3];
    const float* b2  = (const float*)d_in[4];
    const float* eps = (const float*)d_in[5];
    const int*   ei  = (const int*)d_in[6];

    int n = in_sizes[5] / HID;   // 100000
    int e = in_sizes[6] / 2;     // 3200000
    const int* srcs = ei;
    const int* dsts = ei + e;

    // ws layout: [ideg n int][dis n f32][h1 16n f32][agg1 16n f32][hsb 16n u16]
    int*            ideg = (int*)d_ws;
    float*          dis  = (float*)(ideg + n);
    float*          h1   = dis + n;
    float*          agg1 = h1 + (size_t)n * HID;
    unsigned short* hsb  = (unsigned short*)(agg1 + (size_t)n * HID);
    float*          outf = (float*)d_out;

    size_t featBytes = (size_t)n * HID * sizeof(float);
    hipMemsetAsync(ideg, 0, (size_t)n * sizeof(int), stream);
    hipMemsetAsync(agg1, 0, featBytes, stream);
    hipMemsetAsync(outf, 0, featBytes, stream);

    int nBlk    = (n + 255) / 256;
    int eBlk    = (e + 255) / 256;
    int rowBlk  = (n + 15) / 16;
    int featBlk = (n * 16 + 255) / 256;
    int propBlk = (e * 4 + 255) / 256;

    deg_count_int<<<eBlk, 256, 0, stream>>>(dsts, ideg, e);
    make_dis<<<nBlk, 256, 0, stream>>>(ideg, dis, n);

    mm1<<<rowBlk, 256, 0, stream>>>(x, W1, dis, h1, hsb, n);

    prop<<<propBlk, 256, 0, stream>>>(srcs, dsts, hsb, agg1, e);
    mid<<<featBlk, 256, 0, stream>>>(agg1, h1, hsb, dis, b1, W2, n);
    prop<<<propBlk, 256, 0, stream>>>(srcs, dsts, hsb, outf, e);
    finalk<<<featBlk, 256, 0, stream>>>(outf, h1, dis, b2, eps, n);
}